// Round 14
// baseline (290.846 us; speedup 1.0000x reference)
//
#include <hip/hip_runtime.h>
#include <hip/hip_bf16.h>
#include <math.h>

#define DIM 128
#define PSHIFT 10          // 1024 nodes per partition
#define PSZ 1024
#define CHUNK 4096

typedef __attribute__((ext_vector_type(8))) short bf16x8;
typedef __attribute__((ext_vector_type(4))) float f32x4;
typedef __attribute__((ext_vector_type(2))) float f32x2;
typedef unsigned short u16;
typedef unsigned char u8;
typedef unsigned int u32;
typedef unsigned long long u64;

__device__ __forceinline__ u16 f2bf(float x) {
    u32 u = __builtin_bit_cast(u32, x);
    u += 0x7fff + ((u >> 16) & 1);          // RNE
    return (u16)(u >> 16);
}
__device__ __forceinline__ float bf2f(u16 h) {
    return __builtin_bit_cast(float, (u32)h << 16);
}
__device__ __forceinline__ float fsig(float x) {      // fast sigmoid
    return __builtin_amdgcn_rcpf(1.f + __expf(-x));
}
__device__ __forceinline__ float ftanh(float x) {     // fast tanh
    return 1.f - 2.f * __builtin_amdgcn_rcpf(__expf(2.f * x) + 1.f);
}
__device__ __forceinline__ u8 f2fp8(float v) {        // OCP e4m3 via HW cvt
    int pk = __builtin_amdgcn_cvt_pk_fp8_f32(v, v, 0, false);
    return (u8)(pk & 0xff);
}

// ---------------- fused: partition histogram + dtype prep ----------------

__global__ __launch_bounds__(256) void k_prepcount(const int* __restrict__ edst,
                                                   int* __restrict__ pcnt, int E,
                                                   const float* __restrict__ W,
                                                   const float* __restrict__ Wih,
                                                   const float* __restrict__ Whh,
                                                   const float4* __restrict__ xp,
                                                   u16* __restrict__ Wt,
                                                   u16* __restrict__ Wihb,
                                                   u16* __restrict__ Whhb,
                                                   u32* __restrict__ Xpb, int n4) {
    __shared__ int h[128];
    int t = threadIdx.x;
    int gid = blockIdx.x * 256 + t;
    int stride = gridDim.x * 256;
    if (t < 128) h[t] = 0;
    __syncthreads();
    for (int e = gid; e < E; e += stride)
        atomicAdd(&h[edst[e] >> PSHIFT], 1);
    for (int i = gid; i < n4; i += stride) {
        float4 v = xp[i];
        Xpb[i * 2 + 0] = (u32)f2bf(v.x) | ((u32)f2bf(v.y) << 16);
        Xpb[i * 2 + 1] = (u32)f2bf(v.z) | ((u32)f2bf(v.w) << 16);
    }
    if (gid < 128 * 128) {
        int k = gid >> 7, c = gid & 127;
        Wt[c * 128 + k] = f2bf(W[gid]);
    }
    if (gid < 3 * 128 * 128) {
        Wihb[gid] = f2bf(Wih[gid]);
        Whhb[gid] = f2bf(Whh[gid]);
    }
    __syncthreads();
    if (t < 128 && h[t]) atomicAdd(&pcnt[t], h[t]);
}

__global__ __launch_bounds__(256) void k_pscan(const int* __restrict__ pcnt,
                                               int* __restrict__ poff,
                                               int* __restrict__ pfill,
                                               int* __restrict__ rowp,
                                               int P, int N, int E) {
    __shared__ int a[256];
    int t = threadIdx.x;
    int v = (t < P) ? pcnt[t] : 0;
    a[t] = v;
    __syncthreads();
    #pragma unroll
    for (int off = 1; off < 256; off <<= 1) {
        int y = (t >= off) ? a[t - off] : 0;
        __syncthreads();
        a[t] += y;
        __syncthreads();
    }
    int excl = a[t] - v;
    if (t < P) { poff[t] = excl; pfill[t] = excl; }
    if (t == 0) { poff[P] = E; rowp[N] = E; }
}

// scatter packed (src<<PSHIFT | local_dst) u32 into partition buckets.
__global__ __launch_bounds__(256) void k_pscatter(const int* __restrict__ esrc,
                                                  const int* __restrict__ edst,
                                                  int* __restrict__ pfill,
                                                  u32* __restrict__ pbuf, int E) {
    __shared__ int hist[128], gbase[128];
    int t = threadIdx.x;
    int c0 = blockIdx.x * CHUNK;
    int cnt = E - c0; if (cnt > CHUNK) cnt = CHUNK;

    if (t < 128) hist[t] = 0;
    __syncthreads();

    u32 s[16], d[16];
    int p[16], r[16];
    #pragma unroll
    for (int j = 0; j < 16; ++j) {
        int i = j * 256 + t;
        if (i < cnt) {
            s[j] = (u32)esrc[c0 + i];
            d[j] = (u32)edst[c0 + i];
            p[j] = (int)(d[j] >> PSHIFT);
            r[j] = atomicAdd(&hist[p[j]], 1);
        }
    }
    __syncthreads();

    if (t < 128 && hist[t] > 0) gbase[t] = atomicAdd(&pfill[t], hist[t]);
    __syncthreads();

    #pragma unroll
    for (int j = 0; j < 16; ++j) {
        int i = j * 256 + t;
        if (i < cnt)
            pbuf[gbase[p[j]] + r[j]] = (s[j] << PSHIFT) | (d[j] & (PSZ - 1));
    }
}

__global__ __launch_bounds__(256) void k_pfill(const u32* __restrict__ pbuf,
                                               const int* __restrict__ poff,
                                               int* __restrict__ rowp,
                                               int* __restrict__ srcs,
                                               float* __restrict__ dinv, int N) {
    __shared__ int cnt[PSZ];
    __shared__ int wsum[4];
    int p = blockIdx.x, t = threadIdx.x;
    int lane = t & 63, wid = t >> 6;
    int nb0 = p << PSHIFT;
    int ncnt = N - nb0; if (ncnt > PSZ) ncnt = PSZ;
    int b0 = poff[p], b1 = poff[p + 1];
    int bc = b1 - b0;

    for (int i = t; i < PSZ; i += 256) cnt[i] = 0;
    __syncthreads();
    for (int i = t; i < bc; i += 256) {
        u32 ld = pbuf[b0 + i] & (PSZ - 1);
        atomicAdd(&cnt[ld], 1);
    }
    __syncthreads();

    int base = t * 4;
    int c[4];
    int ssum = 0;
    #pragma unroll
    for (int j = 0; j < 4; ++j) { c[j] = cnt[base + j]; ssum += c[j]; }
    int incl = ssum;
    #pragma unroll
    for (int off = 1; off < 64; off <<= 1) {
        int y = __shfl_up(incl, off, 64);
        if (lane >= off) incl += y;
    }
    if (lane == 63) wsum[wid] = incl;
    __syncthreads();
    int add = 0;
    for (int w = 0; w < wid; ++w) add += wsum[w];
    int rr = b0 + add + (incl - ssum);
    #pragma unroll
    for (int j = 0; j < 4; ++j) {
        int i = base + j;
        if (i < ncnt) {
            rowp[nb0 + i] = rr;
            dinv[nb0 + i] = rsqrtf((float)(c[j] + 1));   // +1 self loop
        }
        cnt[i] = rr;     // becomes fill cursor
        rr += c[j];
    }
    __syncthreads();

    for (int i = t; i < bc; i += 256) {
        u32 v = pbuf[b0 + i];
        u32 ld = v & (PSZ - 1);
        int pos = atomicAdd(&cnt[ld], 1);
        srcs[pos] = (int)(v >> PSHIFT);
    }
}

// ---------------- GEMM1 (persistent): XW8 = fp8((bf16(X)@Wt)*dinv) ----
// grid = 768 (3/CU); W staged ONCE; stride loop over 128-row tiles.

__global__ __launch_bounds__(256) void k_gemm1(const float* __restrict__ X,
                                               const u16* __restrict__ Wt,
                                               const float* __restrict__ dinv,
                                               u8* __restrict__ XW8, int n) {
    __shared__ u16 Wlds[128 * 128];   // 32 KB, XOR-swizzled rows
    int t = threadIdx.x, w = t >> 6, l = t & 63;
    int lr = l & 15, q = l >> 4;

    for (int cidx = t; cidx < 2048; cidx += 256) {
        int r = cidx >> 4, kc = cidx & 15;
        int dst = r * 128 + ((kc * 8) ^ ((r & 7) << 3));
        *(bf16x8*)(Wlds + dst) = *(const bf16x8*)(Wt + r * 128 + kc * 8);
    }
    __syncthreads();

    int sw = (lr & 7) << 3;
    int nrb = (n + 127) >> 7;

    #pragma unroll 1
    for (int rb = blockIdx.x; rb < nrb; rb += 768) {
        int wrow0 = rb * 128 + w * 32;
        int ar0 = wrow0 + lr;      if (ar0 > n - 1) ar0 = n - 1;
        int ar1 = wrow0 + 16 + lr; if (ar1 > n - 1) ar1 = n - 1;
        const float* x0 = X + (size_t)ar0 * DIM;
        const float* x1 = X + (size_t)ar1 * DIM;

        f32x4 acc[2][8];
        #pragma unroll
        for (int s = 0; s < 2; ++s)
            #pragma unroll
            for (int c = 0; c < 8; ++c) acc[s][c] = (f32x4){0.f, 0.f, 0.f, 0.f};

        #pragma unroll
        for (int kb = 0; kb < 4; ++kb) {
            int ko = kb * 32 + q * 8;
            float4 f00 = *(const float4*)(x0 + ko), f01 = *(const float4*)(x0 + ko + 4);
            float4 f10 = *(const float4*)(x1 + ko), f11 = *(const float4*)(x1 + ko + 4);
            bf16x8 a0, a1;
            a0[0] = (short)f2bf(f00.x); a0[1] = (short)f2bf(f00.y);
            a0[2] = (short)f2bf(f00.z); a0[3] = (short)f2bf(f00.w);
            a0[4] = (short)f2bf(f01.x); a0[5] = (short)f2bf(f01.y);
            a0[6] = (short)f2bf(f01.z); a0[7] = (short)f2bf(f01.w);
            a1[0] = (short)f2bf(f10.x); a1[1] = (short)f2bf(f10.y);
            a1[2] = (short)f2bf(f10.z); a1[3] = (short)f2bf(f10.w);
            a1[4] = (short)f2bf(f11.x); a1[5] = (short)f2bf(f11.y);
            a1[6] = (short)f2bf(f11.z); a1[7] = (short)f2bf(f11.w);
            int kw = ko ^ sw;
            #pragma unroll
            for (int ct = 0; ct < 8; ++ct) {
                bf16x8 b = *(const bf16x8*)(Wlds + (ct * 16 + lr) * 128 + kw);
                acc[0][ct] = __builtin_amdgcn_mfma_f32_16x16x32_bf16(a0, b, acc[0][ct], 0, 0, 0);
                acc[1][ct] = __builtin_amdgcn_mfma_f32_16x16x32_bf16(a1, b, acc[1][ct], 0, 0, 0);
            }
        }

        float dv[2][4];
        #pragma unroll
        for (int s = 0; s < 2; ++s)
            #pragma unroll
            for (int i = 0; i < 4; ++i) {
                int row = wrow0 + s * 16 + q * 4 + i; if (row > n - 1) row = n - 1;
                dv[s][i] = dinv[row];
            }
        #pragma unroll
        for (int s = 0; s < 2; ++s)
            #pragma unroll
            for (int ct = 0; ct < 8; ++ct)
                #pragma unroll
                for (int i = 0; i < 4; ++i) {
                    int row = wrow0 + s * 16 + q * 4 + i;
                    if (row < n)
                        XW8[(size_t)row * DIM + ct * 16 + lr] = f2fp8(acc[s][ct][i] * dv[s][i]);
                }
    }
}

// ---------------- gather (fp8 in, bf16 out, packed f32x2 acc) ----------

__global__ __launch_bounds__(256) void k_gather(const u8* __restrict__ XW8,
                                                const float* __restrict__ dinv,
                                                const int* __restrict__ row_ptr,
                                                const int* __restrict__ srcs,
                                                const float* __restrict__ bias,
                                                u16* __restrict__ Hcb, int n) {
    int node = blockIdx.x * 4 + (threadIdx.x >> 6);
    if (node >= n) return;
    int lane = threadIdx.x & 63;
    int c = lane * 2;

    u16 sv = *(const u16*)(XW8 + (size_t)node * DIM + c);
    f32x2 acc = __builtin_amdgcn_cvt_pk_f32_fp8((int)(u32)sv, false);  // self

    int e = row_ptr[node], end = row_ptr[node + 1];
    for (; e + 7 < end; e += 8) {
        int sdx[8]; u16 vv[8];
        #pragma unroll
        for (int j = 0; j < 8; ++j) sdx[j] = srcs[e + j];
        #pragma unroll
        for (int j = 0; j < 8; ++j)
            vv[j] = *(const u16*)(XW8 + (size_t)sdx[j] * DIM + c);
        #pragma unroll
        for (int j = 0; j < 8; ++j)
            acc += __builtin_amdgcn_cvt_pk_f32_fp8((int)(u32)vv[j], false);
    }
    for (; e < end; ++e) {
        u16 v = *(const u16*)(XW8 + (size_t)srcs[e] * DIM + c);
        acc += __builtin_amdgcn_cvt_pk_f32_fp8((int)(u32)v, false);
    }
    float di = dinv[node];
    float ox = acc[0] * di + bias[c];
    float oy = acc[1] * di + bias[c + 1];
    *(u32*)(Hcb + (size_t)node * DIM + c) = (u32)f2bf(ox) | ((u32)f2bf(oy) << 16);
}

// ---------------- fused GRU (balanced persistent, cs fixed/block) ------
// grid = 1536 (6/CU exactly). Block: fixed 16-col slice cs; weights staged
// ONCE (24 KB); strides over 128-row tiles (rb = slot; rb += 192).
// XCD placement: the 8 cs-blocks sharing a slot-set sit on ONE XCD
// (b = xcd + 8*(s_local*8 + cs)), so Hcb/Xpb rows are L2-shared 8x.

__global__ __launch_bounds__(256) void k_gru(const u16* __restrict__ Hcb,
                                             const u16* __restrict__ Xpb,
                                             const u16* __restrict__ Wihb,
                                             const u16* __restrict__ Whhb,
                                             const float* __restrict__ bih,
                                             const float* __restrict__ bhh,
                                             float* __restrict__ Out, int n) {
    __shared__ u16 Wlds[96 * 128];   // 24 KB
    int t = threadIdx.x, w = t >> 6, l = t & 63;
    int lr = l & 15, q = l >> 4;

    int b = blockIdx.x;            // 1536
    int xcd = b & 7;
    int local = b >> 3;            // 0..191
    int cs = local & 7;
    int s_local = local >> 3;      // 0..23
    int slot = xcd * 24 + s_local; // 0..191
    int c0 = cs * 16;

    // stage 96 weight rows once: r = m*48 + g*16 + cc  (m: 0=ih, 1=hh)
    for (int cidx = t; cidx < 1536; cidx += 256) {
        int r = cidx >> 4, kc = cidx & 15;
        int m = (r >= 48);
        int rr = m ? r - 48 : r;
        int g = rr >> 4, cc = rr & 15;
        const u16* src = (m ? Whhb : Wihb) + (size_t)((g << 7) + c0 + cc) * DIM + kc * 8;
        int dst = r * 128 + ((kc * 8) ^ ((r & 7) << 3));
        *(bf16x8*)(Wlds + dst) = *(const bf16x8*)src;
    }
    __syncthreads();

    int sw = (lr & 7) << 3;
    int j = c0 + lr;
    float br = bih[j],       bz = bih[128 + j], bn = bih[256 + j];
    float cr = bhh[j],       cz = bhh[128 + j], cn = bhh[256 + j];

    int nrb = (n + 127) >> 7;
    #pragma unroll 1
    for (int rb = slot; rb < nrb; rb += 192) {
        int wrow0 = rb * 128 + w * 32;
        int ar0 = wrow0 + lr;      if (ar0 > n - 1) ar0 = n - 1;
        int ar1 = wrow0 + 16 + lr; if (ar1 > n - 1) ar1 = n - 1;
        const u16* hb0 = Hcb + (size_t)ar0 * DIM;
        const u16* hb1 = Hcb + (size_t)ar1 * DIM;
        const u16* xb0 = Xpb + (size_t)ar0 * DIM;
        const u16* xb1 = Xpb + (size_t)ar1 * DIM;

        f32x4 aI[3][2], aH[3][2];   // [gate][stripe]
        #pragma unroll
        for (int g = 0; g < 3; ++g)
            #pragma unroll
            for (int s = 0; s < 2; ++s) {
                aI[g][s] = (f32x4){0.f, 0.f, 0.f, 0.f};
                aH[g][s] = (f32x4){0.f, 0.f, 0.f, 0.f};
            }

        #pragma unroll
        for (int kb = 0; kb < 4; ++kb) {
            int ko = kb * 32 + q * 8;
            bf16x8 hA0 = *(const bf16x8*)(hb0 + ko);
            bf16x8 hA1 = *(const bf16x8*)(hb1 + ko);
            bf16x8 xA0 = *(const bf16x8*)(xb0 + ko);
            bf16x8 xA1 = *(const bf16x8*)(xb1 + ko);
            int kw = ko ^ sw;
            #pragma unroll
            for (int g = 0; g < 3; ++g) {
                int ridx = (g * 16 + lr) * 128 + kw;
                bf16x8 bI = *(const bf16x8*)(Wlds + ridx);
                bf16x8 bH = *(const bf16x8*)(Wlds + ridx + 48 * 128);
                aI[g][0] = __builtin_amdgcn_mfma_f32_16x16x32_bf16(hA0, bI, aI[g][0], 0, 0, 0);
                aI[g][1] = __builtin_amdgcn_mfma_f32_16x16x32_bf16(hA1, bI, aI[g][1], 0, 0, 0);
                aH[g][0] = __builtin_amdgcn_mfma_f32_16x16x32_bf16(xA0, bH, aH[g][0], 0, 0, 0);
                aH[g][1] = __builtin_amdgcn_mfma_f32_16x16x32_bf16(xA1, bH, aH[g][1], 0, 0, 0);
            }
        }

        #pragma unroll
        for (int s = 0; s < 2; ++s)
            #pragma unroll
            for (int i = 0; i < 4; ++i) {
                int row = wrow0 + s * 16 + q * 4 + i;
                if (row >= n) continue;
                float ir = aI[0][s][i] + br;
                float iz = aI[1][s][i] + bz;
                float in_ = aI[2][s][i] + bn;
                float hr = aH[0][s][i] + cr;
                float hz = aH[1][s][i] + cz;
                float hn = aH[2][s][i] + cn;
                float rg = fsig(ir + hr);
                float zc = fsig(-(iz + hz));          // = 1 - z
                float ng = ftanh(in_ + rg * hn);
                float hp = bf2f((u16)Xpb[(size_t)row * DIM + j]);
                Out[(size_t)row * DIM + j] = fmaf(zc, ng - hp, hp);
            }
    }
}

// ---------------- host launch ----------------

extern "C" void kernel_launch(void* const* d_in, const int* in_sizes, int n_in,
                              void* d_out, int out_size, void* d_ws, size_t ws_size,
                              hipStream_t stream) {
    const float* x     = (const float*)d_in[0];
    const int*   ei    = (const int*)d_in[1];
    const float* xprev = (const float*)d_in[2];
    const float* W     = (const float*)d_in[3];
    const float* b     = (const float*)d_in[4];
    const float* Wih   = (const float*)d_in[5];
    const float* Whh   = (const float*)d_in[6];
    const float* bih   = (const float*)d_in[7];
    const float* bhh   = (const float*)d_in[8];

    int N = in_sizes[0] / DIM;
    int E = in_sizes[1] / 2;
    int P = (N + PSZ - 1) >> PSHIFT;
    const int* esrc = ei;
    const int* edst = ei + E;

    char* p = (char*)d_ws;
    auto alloc = [&](size_t bytes) {
        char* q = p;
        p += (bytes + 255) & ~(size_t)255;
        return q;
    };
    float* dinv = (float*)alloc((size_t)N * 4);
    int*   rowp = (int*)  alloc((size_t)(N + 1) * 4);
    int*   srcs = (int*)  alloc((size_t)E * 4);
    u16*   Hcb  = (u16*)  alloc((size_t)N * DIM * 2);
    u16*   Xpb  = (u16*)  alloc((size_t)N * DIM * 2);
    size_t xwsz = (size_t)N * DIM;             // fp8 bytes
    size_t pbsz = (size_t)E * 4;               // packed pbuf bytes
    u8*    XW8  = (u8*)   alloc(xwsz > pbsz ? xwsz : pbsz);
    u16*   Wt   = (u16*)  alloc(128 * 128 * 2);
    u16*   Wihb = (u16*)  alloc(3 * 128 * 128 * 2);
    u16*   Whhb = (u16*)  alloc(3 * 128 * 128 * 2);
    int*   pcnt = (int*)  alloc(128 * 4);
    int*   poff = (int*)  alloc(129 * 4);
    int*   pfil = (int*)  alloc(128 * 4);
    u32*   pbuf = (u32*)XW8;   // alias: pbuf dead before k_gemm1 writes XW8
    float* out  = (float*)d_out;

    hipMemsetAsync(pcnt, 0, 128 * 4, stream);
    int n4 = N * DIM / 4;
    k_prepcount<<<2048, 256, 0, stream>>>(edst, pcnt, E, W, Wih, Whh,
                                          (const float4*)xprev,
                                          Wt, Wihb, Whhb, (u32*)Xpb, n4);
    k_pscan   <<<1, 256, 0, stream>>>(pcnt, poff, pfil, rowp, P, N, E);
    int nch = (E + CHUNK - 1) / CHUNK;
    k_pscatter<<<nch, 256, 0, stream>>>(esrc, edst, pfil, pbuf, E);
    k_pfill   <<<P, 256, 0, stream>>>(pbuf, poff, rowp, srcs, dinv, N);
    k_gemm1   <<<768, 256, 0, stream>>>(x, Wt, dinv, XW8, N);
    k_gather  <<<(N + 3) / 4, 256, 0, stream>>>(XW8, dinv, rowp, srcs, b, Hcb, N);
    k_gru     <<<1536, 256, 0, stream>>>(Hcb, Xpb, Wihb, Whhb, bih, bhh, out, N);
}

// Round 15
// 273.287 us; speedup vs baseline: 1.0643x; 1.0643x over previous
//
#include <hip/hip_runtime.h>
#include <hip/hip_bf16.h>
#include <math.h>

#define DIM 128
#define PSHIFT 10          // 1024 nodes per partition
#define PSZ 1024
#define CHUNK 4096

typedef __attribute__((ext_vector_type(8))) short bf16x8;
typedef __attribute__((ext_vector_type(4))) float f32x4;
typedef __attribute__((ext_vector_type(2))) float f32x2;
typedef unsigned short u16;
typedef unsigned char u8;
typedef unsigned int u32;
typedef unsigned long long u64;

__device__ __forceinline__ u16 f2bf(float x) {
    u32 u = __builtin_bit_cast(u32, x);
    u += 0x7fff + ((u >> 16) & 1);          // RNE
    return (u16)(u >> 16);
}
__device__ __forceinline__ float bf2f(u16 h) {
    return __builtin_bit_cast(float, (u32)h << 16);
}
__device__ __forceinline__ float fsig(float x) {      // fast sigmoid
    return __builtin_amdgcn_rcpf(1.f + __expf(-x));
}
__device__ __forceinline__ float ftanh(float x) {     // fast tanh
    return 1.f - 2.f * __builtin_amdgcn_rcpf(__expf(2.f * x) + 1.f);
}
__device__ __forceinline__ u8 f2fp8(float v) {        // OCP e4m3 via HW cvt
    int pk = __builtin_amdgcn_cvt_pk_fp8_f32(v, v, 0, false);
    return (u8)(pk & 0xff);
}

// ---------------- fused: partition histogram + dtype prep ----------------

__global__ __launch_bounds__(256) void k_prepcount(const int* __restrict__ edst,
                                                   int* __restrict__ pcnt, int E,
                                                   const float* __restrict__ W,
                                                   const float* __restrict__ Wih,
                                                   const float* __restrict__ Whh,
                                                   const float4* __restrict__ xp,
                                                   u16* __restrict__ Wt,
                                                   u16* __restrict__ Wihb,
                                                   u16* __restrict__ Whhb,
                                                   u32* __restrict__ Xpb, int n4) {
    __shared__ int h[128];
    int t = threadIdx.x;
    int gid = blockIdx.x * 256 + t;
    int stride = gridDim.x * 256;
    if (t < 128) h[t] = 0;
    __syncthreads();
    for (int e = gid; e < E; e += stride)
        atomicAdd(&h[edst[e] >> PSHIFT], 1);
    for (int i = gid; i < n4; i += stride) {
        float4 v = xp[i];
        Xpb[i * 2 + 0] = (u32)f2bf(v.x) | ((u32)f2bf(v.y) << 16);
        Xpb[i * 2 + 1] = (u32)f2bf(v.z) | ((u32)f2bf(v.w) << 16);
    }
    if (gid < 128 * 128) {
        int k = gid >> 7, c = gid & 127;
        Wt[c * 128 + k] = f2bf(W[gid]);
    }
    if (gid < 3 * 128 * 128) {
        Wihb[gid] = f2bf(Wih[gid]);
        Whhb[gid] = f2bf(Whh[gid]);
    }
    __syncthreads();
    if (t < 128 && h[t]) atomicAdd(&pcnt[t], h[t]);
}

__global__ __launch_bounds__(256) void k_pscan(const int* __restrict__ pcnt,
                                               int* __restrict__ poff,
                                               int* __restrict__ pfill,
                                               int* __restrict__ rowp,
                                               int P, int N, int E) {
    __shared__ int a[256];
    int t = threadIdx.x;
    int v = (t < P) ? pcnt[t] : 0;
    a[t] = v;
    __syncthreads();
    #pragma unroll
    for (int off = 1; off < 256; off <<= 1) {
        int y = (t >= off) ? a[t - off] : 0;
        __syncthreads();
        a[t] += y;
        __syncthreads();
    }
    int excl = a[t] - v;
    if (t < P) { poff[t] = excl; pfill[t] = excl; }
    if (t == 0) { poff[P] = E; rowp[N] = E; }
}

// scatter packed (src<<PSHIFT | local_dst) u32 into partition buckets.
__global__ __launch_bounds__(256) void k_pscatter(const int* __restrict__ esrc,
                                                  const int* __restrict__ edst,
                                                  int* __restrict__ pfill,
                                                  u32* __restrict__ pbuf, int E) {
    __shared__ int hist[128], gbase[128];
    int t = threadIdx.x;
    int c0 = blockIdx.x * CHUNK;
    int cnt = E - c0; if (cnt > CHUNK) cnt = CHUNK;

    if (t < 128) hist[t] = 0;
    __syncthreads();

    u32 s[16], d[16];
    int p[16], r[16];
    #pragma unroll
    for (int j = 0; j < 16; ++j) {
        int i = j * 256 + t;
        if (i < cnt) {
            s[j] = (u32)esrc[c0 + i];
            d[j] = (u32)edst[c0 + i];
            p[j] = (int)(d[j] >> PSHIFT);
            r[j] = atomicAdd(&hist[p[j]], 1);
        }
    }
    __syncthreads();

    if (t < 128 && hist[t] > 0) gbase[t] = atomicAdd(&pfill[t], hist[t]);
    __syncthreads();

    #pragma unroll
    for (int j = 0; j < 16; ++j) {
        int i = j * 256 + t;
        if (i < cnt)
            pbuf[gbase[p[j]] + r[j]] = (s[j] << PSHIFT) | (d[j] & (PSZ - 1));
    }
}

__global__ __launch_bounds__(256) void k_pfill(const u32* __restrict__ pbuf,
                                               const int* __restrict__ poff,
                                               int* __restrict__ rowp,
                                               int* __restrict__ srcs,
                                               float* __restrict__ dinv, int N) {
    __shared__ int cnt[PSZ];
    __shared__ int wsum[4];
    int p = blockIdx.x, t = threadIdx.x;
    int lane = t & 63, wid = t >> 6;
    int nb0 = p << PSHIFT;
    int ncnt = N - nb0; if (ncnt > PSZ) ncnt = PSZ;
    int b0 = poff[p], b1 = poff[p + 1];
    int bc = b1 - b0;

    for (int i = t; i < PSZ; i += 256) cnt[i] = 0;
    __syncthreads();
    for (int i = t; i < bc; i += 256) {
        u32 ld = pbuf[b0 + i] & (PSZ - 1);
        atomicAdd(&cnt[ld], 1);
    }
    __syncthreads();

    int base = t * 4;
    int c[4];
    int ssum = 0;
    #pragma unroll
    for (int j = 0; j < 4; ++j) { c[j] = cnt[base + j]; ssum += c[j]; }
    int incl = ssum;
    #pragma unroll
    for (int off = 1; off < 64; off <<= 1) {
        int y = __shfl_up(incl, off, 64);
        if (lane >= off) incl += y;
    }
    if (lane == 63) wsum[wid] = incl;
    __syncthreads();
    int add = 0;
    for (int w = 0; w < wid; ++w) add += wsum[w];
    int rr = b0 + add + (incl - ssum);
    #pragma unroll
    for (int j = 0; j < 4; ++j) {
        int i = base + j;
        if (i < ncnt) {
            rowp[nb0 + i] = rr;
            dinv[nb0 + i] = rsqrtf((float)(c[j] + 1));   // +1 self loop
        }
        cnt[i] = rr;     // becomes fill cursor
        rr += c[j];
    }
    __syncthreads();

    for (int i = t; i < bc; i += 256) {
        u32 v = pbuf[b0 + i];
        u32 ld = v & (PSZ - 1);
        int pos = atomicAdd(&cnt[ld], 1);
        srcs[pos] = (int)(v >> PSHIFT);
    }
}

// ---------------- GEMM1: XW8 = fp8( (bf16(X) @ Wt) * dinv[row] ) -------

__global__ __launch_bounds__(256) void k_gemm1(const float* __restrict__ X,
                                               const u16* __restrict__ Wt,
                                               const float* __restrict__ dinv,
                                               u8* __restrict__ XW8, int n) {
    __shared__ u16 Wlds[128 * 128];   // 32 KB, XOR-swizzled rows
    int t = threadIdx.x, w = t >> 6, l = t & 63;
    int lr = l & 15, q = l >> 4;

    for (int cidx = t; cidx < 2048; cidx += 256) {
        int r = cidx >> 4, kc = cidx & 15;
        int dst = r * 128 + ((kc * 8) ^ ((r & 7) << 3));
        *(bf16x8*)(Wlds + dst) = *(const bf16x8*)(Wt + r * 128 + kc * 8);
    }
    __syncthreads();

    int r0 = blockIdx.x * 128;
    int wrow0 = r0 + w * 32;
    int sw = (lr & 7) << 3;
    int ar0 = wrow0 + lr;      if (ar0 > n - 1) ar0 = n - 1;
    int ar1 = wrow0 + 16 + lr; if (ar1 > n - 1) ar1 = n - 1;
    const float* x0 = X + (size_t)ar0 * DIM;
    const float* x1 = X + (size_t)ar1 * DIM;

    f32x4 acc[2][8];
    #pragma unroll
    for (int s = 0; s < 2; ++s)
        #pragma unroll
        for (int c = 0; c < 8; ++c) acc[s][c] = (f32x4){0.f, 0.f, 0.f, 0.f};

    #pragma unroll
    for (int kb = 0; kb < 4; ++kb) {
        int ko = kb * 32 + q * 8;
        float4 f00 = *(const float4*)(x0 + ko), f01 = *(const float4*)(x0 + ko + 4);
        float4 f10 = *(const float4*)(x1 + ko), f11 = *(const float4*)(x1 + ko + 4);
        bf16x8 a0, a1;
        a0[0] = (short)f2bf(f00.x); a0[1] = (short)f2bf(f00.y);
        a0[2] = (short)f2bf(f00.z); a0[3] = (short)f2bf(f00.w);
        a0[4] = (short)f2bf(f01.x); a0[5] = (short)f2bf(f01.y);
        a0[6] = (short)f2bf(f01.z); a0[7] = (short)f2bf(f01.w);
        a1[0] = (short)f2bf(f10.x); a1[1] = (short)f2bf(f10.y);
        a1[2] = (short)f2bf(f10.z); a1[3] = (short)f2bf(f10.w);
        a1[4] = (short)f2bf(f11.x); a1[5] = (short)f2bf(f11.y);
        a1[6] = (short)f2bf(f11.z); a1[7] = (short)f2bf(f11.w);
        int kw = ko ^ sw;
        #pragma unroll
        for (int ct = 0; ct < 8; ++ct) {
            bf16x8 b = *(const bf16x8*)(Wlds + (ct * 16 + lr) * 128 + kw);
            acc[0][ct] = __builtin_amdgcn_mfma_f32_16x16x32_bf16(a0, b, acc[0][ct], 0, 0, 0);
            acc[1][ct] = __builtin_amdgcn_mfma_f32_16x16x32_bf16(a1, b, acc[1][ct], 0, 0, 0);
        }
    }

    float dv[2][4];
    #pragma unroll
    for (int s = 0; s < 2; ++s)
        #pragma unroll
        for (int i = 0; i < 4; ++i) {
            int row = wrow0 + s * 16 + q * 4 + i; if (row > n - 1) row = n - 1;
            dv[s][i] = dinv[row];
        }
    #pragma unroll
    for (int s = 0; s < 2; ++s)
        #pragma unroll
        for (int ct = 0; ct < 8; ++ct)
            #pragma unroll
            for (int i = 0; i < 4; ++i) {
                int row = wrow0 + s * 16 + q * 4 + i;
                if (row < n)
                    XW8[(size_t)row * DIM + ct * 16 + lr] = f2fp8(acc[s][ct][i] * dv[s][i]);
            }
}

// ---------------- gather (fp8 in, bf16 out, packed f32x2 acc) ----------

__global__ __launch_bounds__(256) void k_gather(const u8* __restrict__ XW8,
                                                const float* __restrict__ dinv,
                                                const int* __restrict__ row_ptr,
                                                const int* __restrict__ srcs,
                                                const float* __restrict__ bias,
                                                u16* __restrict__ Hcb, int n) {
    int node = blockIdx.x * 4 + (threadIdx.x >> 6);
    if (node >= n) return;
    int lane = threadIdx.x & 63;
    int c = lane * 2;

    u16 sv = *(const u16*)(XW8 + (size_t)node * DIM + c);
    f32x2 acc = __builtin_amdgcn_cvt_pk_f32_fp8((int)(u32)sv, false);  // self

    int e = row_ptr[node], end = row_ptr[node + 1];
    for (; e + 7 < end; e += 8) {
        int sdx[8]; u16 vv[8];
        #pragma unroll
        for (int j = 0; j < 8; ++j) sdx[j] = srcs[e + j];
        #pragma unroll
        for (int j = 0; j < 8; ++j)
            vv[j] = *(const u16*)(XW8 + (size_t)sdx[j] * DIM + c);
        #pragma unroll
        for (int j = 0; j < 8; ++j)
            acc += __builtin_amdgcn_cvt_pk_f32_fp8((int)(u32)vv[j], false);
    }
    for (; e < end; ++e) {
        u16 v = *(const u16*)(XW8 + (size_t)srcs[e] * DIM + c);
        acc += __builtin_amdgcn_cvt_pk_f32_fp8((int)(u32)v, false);
    }
    float di = dinv[node];
    float ox = acc[0] * di + bias[c];
    float oy = acc[1] * di + bias[c + 1];
    *(u32*)(Hcb + (size_t)node * DIM + c) = (u32)f2bf(ox) | ((u32)f2bf(oy) << 16);
}

// ---------------- fused GRU (r13 structure + hp prefetch) --------------
// block = 512 rows x 16 cols; stage 24 KB once, then four 128-row chunks.
// hp (h_prev) loads issued BEFORE the MFMA loop so L2 latency hides.

__global__ __launch_bounds__(256) void k_gru(const u16* __restrict__ Hcb,
                                             const u16* __restrict__ Xpb,
                                             const u16* __restrict__ Wihb,
                                             const u16* __restrict__ Whhb,
                                             const float* __restrict__ bih,
                                             const float* __restrict__ bhh,
                                             float* __restrict__ Out, int n) {
    __shared__ u16 Wlds[96 * 128];   // 24 KB
    int t = threadIdx.x, w = t >> 6, l = t & 63;
    int lr = l & 15, q = l >> 4;

    // bijective XCD-chunk transform (m204)
    int nwg = gridDim.x;
    int qq = nwg >> 3, rr8 = nwg & 7;
    int xcd = blockIdx.x & 7, idx = blockIdx.x >> 3;
    int logical = (xcd < rr8 ? xcd * (qq + 1) : rr8 * (qq + 1) + (xcd - rr8) * qq) + idx;
    int cs = logical & 7;
    int rb = logical >> 3;
    int c0 = cs * 16;
    int r0 = rb * 512;

    // stage 96 weight rows: r = m*48 + g*16 + cc  (m: 0=ih, 1=hh)
    for (int cidx = t; cidx < 1536; cidx += 256) {
        int r = cidx >> 4, kc = cidx & 15;
        int m = (r >= 48);
        int rr = m ? r - 48 : r;
        int g = rr >> 4, cc = rr & 15;
        const u16* src = (m ? Whhb : Wihb) + (size_t)((g << 7) + c0 + cc) * DIM + kc * 8;
        int dst = r * 128 + ((kc * 8) ^ ((r & 7) << 3));
        *(bf16x8*)(Wlds + dst) = *(const bf16x8*)src;
    }
    __syncthreads();

    int sw = (lr & 7) << 3;
    int j = c0 + lr;
    float br = bih[j],       bz = bih[128 + j], bn = bih[256 + j];
    float cr = bhh[j],       cz = bhh[128 + j], cn = bhh[256 + j];

    #pragma unroll 1
    for (int half = 0; half < 4; ++half) {
        int wrow0 = r0 + half * 128 + w * 32;
        if (wrow0 >= n) break;
        int ar0 = wrow0 + lr;      if (ar0 > n - 1) ar0 = n - 1;
        int ar1 = wrow0 + 16 + lr; if (ar1 > n - 1) ar1 = n - 1;
        const u16* hb0 = Hcb + (size_t)ar0 * DIM;
        const u16* hb1 = Hcb + (size_t)ar1 * DIM;
        const u16* xb0 = Xpb + (size_t)ar0 * DIM;
        const u16* xb1 = Xpb + (size_t)ar1 * DIM;

        // issue epilogue hp loads EARLY (latency hides under MFMA loop)
        u16 hp16[2][4];
        #pragma unroll
        for (int s = 0; s < 2; ++s)
            #pragma unroll
            for (int i = 0; i < 4; ++i) {
                int row = wrow0 + s * 16 + q * 4 + i; if (row > n - 1) row = n - 1;
                hp16[s][i] = Xpb[(size_t)row * DIM + j];
            }

        f32x4 aI[3][2], aH[3][2];   // [gate][stripe]
        #pragma unroll
        for (int g = 0; g < 3; ++g)
            #pragma unroll
            for (int s = 0; s < 2; ++s) {
                aI[g][s] = (f32x4){0.f, 0.f, 0.f, 0.f};
                aH[g][s] = (f32x4){0.f, 0.f, 0.f, 0.f};
            }

        #pragma unroll
        for (int kb = 0; kb < 4; ++kb) {
            int ko = kb * 32 + q * 8;
            bf16x8 hA0 = *(const bf16x8*)(hb0 + ko);
            bf16x8 hA1 = *(const bf16x8*)(hb1 + ko);
            bf16x8 xA0 = *(const bf16x8*)(xb0 + ko);
            bf16x8 xA1 = *(const bf16x8*)(xb1 + ko);
            int kw = ko ^ sw;
            #pragma unroll
            for (int g = 0; g < 3; ++g) {
                int ridx = (g * 16 + lr) * 128 + kw;
                bf16x8 bI = *(const bf16x8*)(Wlds + ridx);
                bf16x8 bH = *(const bf16x8*)(Wlds + ridx + 48 * 128);
                aI[g][0] = __builtin_amdgcn_mfma_f32_16x16x32_bf16(hA0, bI, aI[g][0], 0, 0, 0);
                aI[g][1] = __builtin_amdgcn_mfma_f32_16x16x32_bf16(hA1, bI, aI[g][1], 0, 0, 0);
                aH[g][0] = __builtin_amdgcn_mfma_f32_16x16x32_bf16(xA0, bH, aH[g][0], 0, 0, 0);
                aH[g][1] = __builtin_amdgcn_mfma_f32_16x16x32_bf16(xA1, bH, aH[g][1], 0, 0, 0);
            }
        }

        #pragma unroll
        for (int s = 0; s < 2; ++s)
            #pragma unroll
            for (int i = 0; i < 4; ++i) {
                int row = wrow0 + s * 16 + q * 4 + i;
                if (row >= n) continue;
                float ir = aI[0][s][i] + br;
                float iz = aI[1][s][i] + bz;
                float in_ = aI[2][s][i] + bn;
                float hr = aH[0][s][i] + cr;
                float hz = aH[1][s][i] + cz;
                float hn = aH[2][s][i] + cn;
                float rg = fsig(ir + hr);
                float zc = fsig(-(iz + hz));          // = 1 - z
                float ng = ftanh(in_ + rg * hn);
                float hp = bf2f(hp16[s][i]);
                Out[(size_t)row * DIM + j] = fmaf(zc, ng - hp, hp);
            }
    }
}

// ---------------- host launch ----------------

extern "C" void kernel_launch(void* const* d_in, const int* in_sizes, int n_in,
                              void* d_out, int out_size, void* d_ws, size_t ws_size,
                              hipStream_t stream) {
    const float* x     = (const float*)d_in[0];
    const int*   ei    = (const int*)d_in[1];
    const float* xprev = (const float*)d_in[2];
    const float* W     = (const float*)d_in[3];
    const float* b     = (const float*)d_in[4];
    const float* Wih   = (const float*)d_in[5];
    const float* Whh   = (const float*)d_in[6];
    const float* bih   = (const float*)d_in[7];
    const float* bhh   = (const float*)d_in[8];

    int N = in_sizes[0] / DIM;
    int E = in_sizes[1] / 2;
    int P = (N + PSZ - 1) >> PSHIFT;
    const int* esrc = ei;
    const int* edst = ei + E;

    char* p = (char*)d_ws;
    auto alloc = [&](size_t bytes) {
        char* q = p;
        p += (bytes + 255) & ~(size_t)255;
        return q;
    };
    float* dinv = (float*)alloc((size_t)N * 4);
    int*   rowp = (int*)  alloc((size_t)(N + 1) * 4);
    int*   srcs = (int*)  alloc((size_t)E * 4);
    u16*   Hcb  = (u16*)  alloc((size_t)N * DIM * 2);
    u16*   Xpb  = (u16*)  alloc((size_t)N * DIM * 2);
    size_t xwsz = (size_t)N * DIM;             // fp8 bytes
    size_t pbsz = (size_t)E * 4;               // packed pbuf bytes
    u8*    XW8  = (u8*)   alloc(xwsz > pbsz ? xwsz : pbsz);
    u16*   Wt   = (u16*)  alloc(128 * 128 * 2);
    u16*   Wihb = (u16*)  alloc(3 * 128 * 128 * 2);
    u16*   Whhb = (u16*)  alloc(3 * 128 * 128 * 2);
    int*   pcnt = (int*)  alloc(128 * 4);
    int*   poff = (int*)  alloc(129 * 4);
    int*   pfil = (int*)  alloc(128 * 4);
    u32*   pbuf = (u32*)XW8;   // alias: pbuf dead before k_gemm1 writes XW8
    float* out  = (float*)d_out;

    hipMemsetAsync(pcnt, 0, 128 * 4, stream);
    int n4 = N * DIM / 4;
    k_prepcount<<<2048, 256, 0, stream>>>(edst, pcnt, E, W, Wih, Whh,
                                          (const float4*)xprev,
                                          Wt, Wihb, Whhb, (u32*)Xpb, n4);
    k_pscan   <<<1, 256, 0, stream>>>(pcnt, poff, pfil, rowp, P, N, E);
    int nch = (E + CHUNK - 1) / CHUNK;
    k_pscatter<<<nch, 256, 0, stream>>>(esrc, edst, pfil, pbuf, E);
    k_pfill   <<<P, 256, 0, stream>>>(pbuf, poff, rowp, srcs, dinv, N);
    int nrb = (N + 127) / 128;
    k_gemm1   <<<nrb, 256, 0, stream>>>(x, Wt, dinv, XW8, N);
    k_gather  <<<(N + 3) / 4, 256, 0, stream>>>(XW8, dinv, rowp, srcs, b, Hcb, N);
    int ngb = (N + 511) / 512;
    k_gru     <<<ngb * 8, 256, 0, stream>>>(Hcb, Xpb, Wihb, Whhb, bih, bhh, out, N);
}

// Round 16
// 269.348 us; speedup vs baseline: 1.0798x; 1.0146x over previous
//
#include <hip/hip_runtime.h>
#include <hip/hip_bf16.h>
#include <math.h>

#define DIM 128
#define PSHIFT 10          // 1024 nodes per partition
#define PSZ 1024
#define CHUNK 4096

typedef __attribute__((ext_vector_type(8))) short bf16x8;
typedef __attribute__((ext_vector_type(4))) float f32x4;
typedef __attribute__((ext_vector_type(2))) float f32x2;
typedef unsigned short u16;
typedef unsigned char u8;
typedef unsigned int u32;
typedef unsigned long long u64;

__device__ __forceinline__ u16 f2bf(float x) {
    u32 u = __builtin_bit_cast(u32, x);
    u += 0x7fff + ((u >> 16) & 1);          // RNE
    return (u16)(u >> 16);
}
__device__ __forceinline__ float bf2f(u16 h) {
    return __builtin_bit_cast(float, (u32)h << 16);
}
__device__ __forceinline__ float fsig(float x) {      // fast sigmoid
    return __builtin_amdgcn_rcpf(1.f + __expf(-x));
}
__device__ __forceinline__ float ftanh(float x) {     // fast tanh
    return 1.f - 2.f * __builtin_amdgcn_rcpf(__expf(2.f * x) + 1.f);
}
__device__ __forceinline__ u8 f2fp8(float v) {        // OCP e4m3 via HW cvt
    int pk = __builtin_amdgcn_cvt_pk_fp8_f32(v, v, 0, false);
    return (u8)(pk & 0xff);
}

// ---------------- fused: partition histogram + dtype prep ----------------

__global__ __launch_bounds__(256) void k_prepcount(const int* __restrict__ edst,
                                                   int* __restrict__ pcnt, int E,
                                                   const float* __restrict__ W,
                                                   const float* __restrict__ Wih,
                                                   const float* __restrict__ Whh,
                                                   const float4* __restrict__ xp,
                                                   u16* __restrict__ Wt,
                                                   u16* __restrict__ Wihb,
                                                   u16* __restrict__ Whhb,
                                                   u32* __restrict__ Xpb, int n4) {
    __shared__ int h[128];
    int t = threadIdx.x;
    int gid = blockIdx.x * 256 + t;
    int stride = gridDim.x * 256;
    if (t < 128) h[t] = 0;
    __syncthreads();
    for (int e = gid; e < E; e += stride)
        atomicAdd(&h[edst[e] >> PSHIFT], 1);
    for (int i = gid; i < n4; i += stride) {
        float4 v = xp[i];
        Xpb[i * 2 + 0] = (u32)f2bf(v.x) | ((u32)f2bf(v.y) << 16);
        Xpb[i * 2 + 1] = (u32)f2bf(v.z) | ((u32)f2bf(v.w) << 16);
    }
    if (gid < 128 * 128) {
        int k = gid >> 7, c = gid & 127;
        Wt[c * 128 + k] = f2bf(W[gid]);
    }
    if (gid < 3 * 128 * 128) {
        Wihb[gid] = f2bf(Wih[gid]);
        Whhb[gid] = f2bf(Whh[gid]);
    }
    __syncthreads();
    if (t < 128 && h[t]) atomicAdd(&pcnt[t], h[t]);
}

__global__ __launch_bounds__(256) void k_pscan(const int* __restrict__ pcnt,
                                               int* __restrict__ poff,
                                               int* __restrict__ pfill,
                                               int* __restrict__ rowp,
                                               int P, int N, int E) {
    __shared__ int a[256];
    int t = threadIdx.x;
    int v = (t < P) ? pcnt[t] : 0;
    a[t] = v;
    __syncthreads();
    #pragma unroll
    for (int off = 1; off < 256; off <<= 1) {
        int y = (t >= off) ? a[t - off] : 0;
        __syncthreads();
        a[t] += y;
        __syncthreads();
    }
    int excl = a[t] - v;
    if (t < P) { poff[t] = excl; pfill[t] = excl; }
    if (t == 0) { poff[P] = E; rowp[N] = E; }
}

// scatter packed (src<<PSHIFT | local_dst) u32 into partition buckets.
__global__ __launch_bounds__(256) void k_pscatter(const int* __restrict__ esrc,
                                                  const int* __restrict__ edst,
                                                  int* __restrict__ pfill,
                                                  u32* __restrict__ pbuf, int E) {
    __shared__ int hist[128], gbase[128];
    int t = threadIdx.x;
    int c0 = blockIdx.x * CHUNK;
    int cnt = E - c0; if (cnt > CHUNK) cnt = CHUNK;

    if (t < 128) hist[t] = 0;
    __syncthreads();

    u32 s[16], d[16];
    int p[16], r[16];
    #pragma unroll
    for (int j = 0; j < 16; ++j) {
        int i = j * 256 + t;
        if (i < cnt) {
            s[j] = (u32)esrc[c0 + i];
            d[j] = (u32)edst[c0 + i];
            p[j] = (int)(d[j] >> PSHIFT);
            r[j] = atomicAdd(&hist[p[j]], 1);
        }
    }
    __syncthreads();

    if (t < 128 && hist[t] > 0) gbase[t] = atomicAdd(&pfill[t], hist[t]);
    __syncthreads();

    #pragma unroll
    for (int j = 0; j < 16; ++j) {
        int i = j * 256 + t;
        if (i < cnt)
            pbuf[gbase[p[j]] + r[j]] = (s[j] << PSHIFT) | (d[j] & (PSZ - 1));
    }
}

__global__ __launch_bounds__(256) void k_pfill(const u32* __restrict__ pbuf,
                                               const int* __restrict__ poff,
                                               int* __restrict__ rowp,
                                               int* __restrict__ srcs,
                                               float* __restrict__ dinv, int N) {
    __shared__ int cnt[PSZ];
    __shared__ int wsum[4];
    int p = blockIdx.x, t = threadIdx.x;
    int lane = t & 63, wid = t >> 6;
    int nb0 = p << PSHIFT;
    int ncnt = N - nb0; if (ncnt > PSZ) ncnt = PSZ;
    int b0 = poff[p], b1 = poff[p + 1];
    int bc = b1 - b0;

    for (int i = t; i < PSZ; i += 256) cnt[i] = 0;
    __syncthreads();
    for (int i = t; i < bc; i += 256) {
        u32 ld = pbuf[b0 + i] & (PSZ - 1);
        atomicAdd(&cnt[ld], 1);
    }
    __syncthreads();

    int base = t * 4;
    int c[4];
    int ssum = 0;
    #pragma unroll
    for (int j = 0; j < 4; ++j) { c[j] = cnt[base + j]; ssum += c[j]; }
    int incl = ssum;
    #pragma unroll
    for (int off = 1; off < 64; off <<= 1) {
        int y = __shfl_up(incl, off, 64);
        if (lane >= off) incl += y;
    }
    if (lane == 63) wsum[wid] = incl;
    __syncthreads();
    int add = 0;
    for (int w = 0; w < wid; ++w) add += wsum[w];
    int rr = b0 + add + (incl - ssum);
    #pragma unroll
    for (int j = 0; j < 4; ++j) {
        int i = base + j;
        if (i < ncnt) {
            rowp[nb0 + i] = rr;
            dinv[nb0 + i] = rsqrtf((float)(c[j] + 1));   // +1 self loop
        }
        cnt[i] = rr;     // becomes fill cursor
        rr += c[j];
    }
    __syncthreads();

    for (int i = t; i < bc; i += 256) {
        u32 v = pbuf[b0 + i];
        u32 ld = v & (PSZ - 1);
        int pos = atomicAdd(&cnt[ld], 1);
        srcs[pos] = (int)(v >> PSHIFT);
    }
}

// ---------------- GEMM1: XW8 = fp8( (bf16(X) @ Wt) * dinv[row] ) -------

__global__ __launch_bounds__(256) void k_gemm1(const float* __restrict__ X,
                                               const u16* __restrict__ Wt,
                                               const float* __restrict__ dinv,
                                               u8* __restrict__ XW8, int n) {
    __shared__ u16 Wlds[128 * 128];   // 32 KB, XOR-swizzled rows
    int t = threadIdx.x, w = t >> 6, l = t & 63;
    int lr = l & 15, q = l >> 4;

    for (int cidx = t; cidx < 2048; cidx += 256) {
        int r = cidx >> 4, kc = cidx & 15;
        int dst = r * 128 + ((kc * 8) ^ ((r & 7) << 3));
        *(bf16x8*)(Wlds + dst) = *(const bf16x8*)(Wt + r * 128 + kc * 8);
    }
    __syncthreads();

    int r0 = blockIdx.x * 128;
    int wrow0 = r0 + w * 32;
    int sw = (lr & 7) << 3;
    int ar0 = wrow0 + lr;      if (ar0 > n - 1) ar0 = n - 1;
    int ar1 = wrow0 + 16 + lr; if (ar1 > n - 1) ar1 = n - 1;
    const float* x0 = X + (size_t)ar0 * DIM;
    const float* x1 = X + (size_t)ar1 * DIM;

    f32x4 acc[2][8];
    #pragma unroll
    for (int s = 0; s < 2; ++s)
        #pragma unroll
        for (int c = 0; c < 8; ++c) acc[s][c] = (f32x4){0.f, 0.f, 0.f, 0.f};

    #pragma unroll
    for (int kb = 0; kb < 4; ++kb) {
        int ko = kb * 32 + q * 8;
        float4 f00 = *(const float4*)(x0 + ko), f01 = *(const float4*)(x0 + ko + 4);
        float4 f10 = *(const float4*)(x1 + ko), f11 = *(const float4*)(x1 + ko + 4);
        bf16x8 a0, a1;
        a0[0] = (short)f2bf(f00.x); a0[1] = (short)f2bf(f00.y);
        a0[2] = (short)f2bf(f00.z); a0[3] = (short)f2bf(f00.w);
        a0[4] = (short)f2bf(f01.x); a0[5] = (short)f2bf(f01.y);
        a0[6] = (short)f2bf(f01.z); a0[7] = (short)f2bf(f01.w);
        a1[0] = (short)f2bf(f10.x); a1[1] = (short)f2bf(f10.y);
        a1[2] = (short)f2bf(f10.z); a1[3] = (short)f2bf(f10.w);
        a1[4] = (short)f2bf(f11.x); a1[5] = (short)f2bf(f11.y);
        a1[6] = (short)f2bf(f11.z); a1[7] = (short)f2bf(f11.w);
        int kw = ko ^ sw;
        #pragma unroll
        for (int ct = 0; ct < 8; ++ct) {
            bf16x8 b = *(const bf16x8*)(Wlds + (ct * 16 + lr) * 128 + kw);
            acc[0][ct] = __builtin_amdgcn_mfma_f32_16x16x32_bf16(a0, b, acc[0][ct], 0, 0, 0);
            acc[1][ct] = __builtin_amdgcn_mfma_f32_16x16x32_bf16(a1, b, acc[1][ct], 0, 0, 0);
        }
    }

    float dv[2][4];
    #pragma unroll
    for (int s = 0; s < 2; ++s)
        #pragma unroll
        for (int i = 0; i < 4; ++i) {
            int row = wrow0 + s * 16 + q * 4 + i; if (row > n - 1) row = n - 1;
            dv[s][i] = dinv[row];
        }
    #pragma unroll
    for (int s = 0; s < 2; ++s)
        #pragma unroll
        for (int ct = 0; ct < 8; ++ct)
            #pragma unroll
            for (int i = 0; i < 4; ++i) {
                int row = wrow0 + s * 16 + q * 4 + i;
                if (row < n)
                    XW8[(size_t)row * DIM + ct * 16 + lr] = f2fp8(acc[s][ct][i] * dv[s][i]);
            }
}

// ---------------- gather (fp8 in, bf16 out, MLP-16 burst) --------------

__global__ __launch_bounds__(256) void k_gather(const u8* __restrict__ XW8,
                                                const float* __restrict__ dinv,
                                                const int* __restrict__ row_ptr,
                                                const int* __restrict__ srcs,
                                                const float* __restrict__ bias,
                                                u16* __restrict__ Hcb, int n) {
    int node = blockIdx.x * 4 + (threadIdx.x >> 6);
    if (node >= n) return;
    int lane = threadIdx.x & 63;
    int c = lane * 2;

    u16 sv = *(const u16*)(XW8 + (size_t)node * DIM + c);
    f32x2 acc = __builtin_amdgcn_cvt_pk_f32_fp8((int)(u32)sv, false);  // self

    int e = row_ptr[node], end = row_ptr[node + 1];
    // 16-wide bursts: all 16 index loads then all 16 row loads in flight
    for (; e + 15 < end; e += 16) {
        int sdx[16]; u16 vv[16];
        #pragma unroll
        for (int j = 0; j < 16; ++j) sdx[j] = srcs[e + j];
        #pragma unroll
        for (int j = 0; j < 16; ++j)
            vv[j] = *(const u16*)(XW8 + (size_t)sdx[j] * DIM + c);
        #pragma unroll
        for (int j = 0; j < 16; ++j)
            acc += __builtin_amdgcn_cvt_pk_f32_fp8((int)(u32)vv[j], false);
    }
    for (; e + 7 < end; e += 8) {
        int sdx[8]; u16 vv[8];
        #pragma unroll
        for (int j = 0; j < 8; ++j) sdx[j] = srcs[e + j];
        #pragma unroll
        for (int j = 0; j < 8; ++j)
            vv[j] = *(const u16*)(XW8 + (size_t)sdx[j] * DIM + c);
        #pragma unroll
        for (int j = 0; j < 8; ++j)
            acc += __builtin_amdgcn_cvt_pk_f32_fp8((int)(u32)vv[j], false);
    }
    for (; e < end; ++e) {
        u16 v = *(const u16*)(XW8 + (size_t)srcs[e] * DIM + c);
        acc += __builtin_amdgcn_cvt_pk_f32_fp8((int)(u32)v, false);
    }
    float di = dinv[node];
    float ox = acc[0] * di + bias[c];
    float oy = acc[1] * di + bias[c + 1];
    *(u32*)(Hcb + (size_t)node * DIM + c) = (u32)f2bf(ox) | ((u32)f2bf(oy) << 16);
}

// ---------------- fused GRU (r13 structure, 4-chunk staging amortize) --
// block = 512 rows x 16 cols; stage 24 KB once, then four 128-row chunks.

__global__ __launch_bounds__(256) void k_gru(const u16* __restrict__ Hcb,
                                             const u16* __restrict__ Xpb,
                                             const u16* __restrict__ Wihb,
                                             const u16* __restrict__ Whhb,
                                             const float* __restrict__ bih,
                                             const float* __restrict__ bhh,
                                             float* __restrict__ Out, int n) {
    __shared__ u16 Wlds[96 * 128];   // 24 KB
    int t = threadIdx.x, w = t >> 6, l = t & 63;
    int lr = l & 15, q = l >> 4;

    // bijective XCD-chunk transform (m204)
    int nwg = gridDim.x;
    int qq = nwg >> 3, rr8 = nwg & 7;
    int xcd = blockIdx.x & 7, idx = blockIdx.x >> 3;
    int logical = (xcd < rr8 ? xcd * (qq + 1) : rr8 * (qq + 1) + (xcd - rr8) * qq) + idx;
    int cs = logical & 7;
    int rb = logical >> 3;
    int c0 = cs * 16;
    int r0 = rb * 512;

    // stage 96 weight rows: r = m*48 + g*16 + cc  (m: 0=ih, 1=hh)
    for (int cidx = t; cidx < 1536; cidx += 256) {
        int r = cidx >> 4, kc = cidx & 15;
        int m = (r >= 48);
        int rr = m ? r - 48 : r;
        int g = rr >> 4, cc = rr & 15;
        const u16* src = (m ? Whhb : Wihb) + (size_t)((g << 7) + c0 + cc) * DIM + kc * 8;
        int dst = r * 128 + ((kc * 8) ^ ((r & 7) << 3));
        *(bf16x8*)(Wlds + dst) = *(const bf16x8*)src;
    }
    __syncthreads();

    int sw = (lr & 7) << 3;
    int j = c0 + lr;
    float br = bih[j],       bz = bih[128 + j], bn = bih[256 + j];
    float cr = bhh[j],       cz = bhh[128 + j], cn = bhh[256 + j];

    #pragma unroll 1
    for (int half = 0; half < 4; ++half) {
        int wrow0 = r0 + half * 128 + w * 32;
        if (wrow0 >= n) break;
        int ar0 = wrow0 + lr;      if (ar0 > n - 1) ar0 = n - 1;
        int ar1 = wrow0 + 16 + lr; if (ar1 > n - 1) ar1 = n - 1;
        const u16* hb0 = Hcb + (size_t)ar0 * DIM;
        const u16* hb1 = Hcb + (size_t)ar1 * DIM;
        const u16* xb0 = Xpb + (size_t)ar0 * DIM;
        const u16* xb1 = Xpb + (size_t)ar1 * DIM;

        f32x4 aI[3][2], aH[3][2];   // [gate][stripe]
        #pragma unroll
        for (int g = 0; g < 3; ++g)
            #pragma unroll
            for (int s = 0; s < 2; ++s) {
                aI[g][s] = (f32x4){0.f, 0.f, 0.f, 0.f};
                aH[g][s] = (f32x4){0.f, 0.f, 0.f, 0.f};
            }

        #pragma unroll
        for (int kb = 0; kb < 4; ++kb) {
            int ko = kb * 32 + q * 8;
            bf16x8 hA0 = *(const bf16x8*)(hb0 + ko);
            bf16x8 hA1 = *(const bf16x8*)(hb1 + ko);
            bf16x8 xA0 = *(const bf16x8*)(xb0 + ko);
            bf16x8 xA1 = *(const bf16x8*)(xb1 + ko);
            int kw = ko ^ sw;
            #pragma unroll
            for (int g = 0; g < 3; ++g) {
                int ridx = (g * 16 + lr) * 128 + kw;
                bf16x8 bI = *(const bf16x8*)(Wlds + ridx);
                bf16x8 bH = *(const bf16x8*)(Wlds + ridx + 48 * 128);
                aI[g][0] = __builtin_amdgcn_mfma_f32_16x16x32_bf16(hA0, bI, aI[g][0], 0, 0, 0);
                aI[g][1] = __builtin_amdgcn_mfma_f32_16x16x32_bf16(hA1, bI, aI[g][1], 0, 0, 0);
                aH[g][0] = __builtin_amdgcn_mfma_f32_16x16x32_bf16(xA0, bH, aH[g][0], 0, 0, 0);
                aH[g][1] = __builtin_amdgcn_mfma_f32_16x16x32_bf16(xA1, bH, aH[g][1], 0, 0, 0);
            }
        }

        #pragma unroll
        for (int s = 0; s < 2; ++s)
            #pragma unroll
            for (int i = 0; i < 4; ++i) {
                int row = wrow0 + s * 16 + q * 4 + i;
                if (row >= n) continue;
                float ir = aI[0][s][i] + br;
                float iz = aI[1][s][i] + bz;
                float in_ = aI[2][s][i] + bn;
                float hr = aH[0][s][i] + cr;
                float hz = aH[1][s][i] + cz;
                float hn = aH[2][s][i] + cn;
                float rg = fsig(ir + hr);
                float zc = fsig(-(iz + hz));          // = 1 - z
                float ng = ftanh(in_ + rg * hn);
                float hp = bf2f((u16)Xpb[(size_t)row * DIM + j]);
                Out[(size_t)row * DIM + j] = fmaf(zc, ng - hp, hp);
            }
    }
}

// ---------------- host launch ----------------

extern "C" void kernel_launch(void* const* d_in, const int* in_sizes, int n_in,
                              void* d_out, int out_size, void* d_ws, size_t ws_size,
                              hipStream_t stream) {
    const float* x     = (const float*)d_in[0];
    const int*   ei    = (const int*)d_in[1];
    const float* xprev = (const float*)d_in[2];
    const float* W     = (const float*)d_in[3];
    const float* b     = (const float*)d_in[4];
    const float* Wih   = (const float*)d_in[5];
    const float* Whh   = (const float*)d_in[6];
    const float* bih   = (const float*)d_in[7];
    const float* bhh   = (const float*)d_in[8];

    int N = in_sizes[0] / DIM;
    int E = in_sizes[1] / 2;
    int P = (N + PSZ - 1) >> PSHIFT;
    const int* esrc = ei;
    const int* edst = ei + E;

    char* p = (char*)d_ws;
    auto alloc = [&](size_t bytes) {
        char* q = p;
        p += (bytes + 255) & ~(size_t)255;
        return q;
    };
    float* dinv = (float*)alloc((size_t)N * 4);
    int*   rowp = (int*)  alloc((size_t)(N + 1) * 4);
    int*   srcs = (int*)  alloc((size_t)E * 4);
    u16*   Hcb  = (u16*)  alloc((size_t)N * DIM * 2);
    u16*   Xpb  = (u16*)  alloc((size_t)N * DIM * 2);
    size_t xwsz = (size_t)N * DIM;             // fp8 bytes
    size_t pbsz = (size_t)E * 4;               // packed pbuf bytes
    u8*    XW8  = (u8*)   alloc(xwsz > pbsz ? xwsz : pbsz);
    u16*   Wt   = (u16*)  alloc(128 * 128 * 2);
    u16*   Wihb = (u16*)  alloc(3 * 128 * 128 * 2);
    u16*   Whhb = (u16*)  alloc(3 * 128 * 128 * 2);
    int*   pcnt = (int*)  alloc(128 * 4);
    int*   poff = (int*)  alloc(129 * 4);
    int*   pfil = (int*)  alloc(128 * 4);
    u32*   pbuf = (u32*)XW8;   // alias: pbuf dead before k_gemm1 writes XW8
    float* out  = (float*)d_out;

    hipMemsetAsync(pcnt, 0, 128 * 4, stream);
    int n4 = N * DIM / 4;
    k_prepcount<<<2048, 256, 0, stream>>>(edst, pcnt, E, W, Wih, Whh,
                                          (const float4*)xprev,
                                          Wt, Wihb, Whhb, (u32*)Xpb, n4);
    k_pscan   <<<1, 256, 0, stream>>>(pcnt, poff, pfil, rowp, P, N, E);
    int nch = (E + CHUNK - 1) / CHUNK;
    k_pscatter<<<nch, 256, 0, stream>>>(esrc, edst, pfil, pbuf, E);
    k_pfill   <<<P, 256, 0, stream>>>(pbuf, poff, rowp, srcs, dinv, N);
    int nrb = (N + 127) / 128;
    k_gemm1   <<<nrb, 256, 0, stream>>>(x, Wt, dinv, XW8, N);
    k_gather  <<<(N + 3) / 4, 256, 0, stream>>>(XW8, dinv, rowp, srcs, b, Hcb, N);
    int ngb = (N + 511) / 512;
    k_gru     <<<ngb * 8, 256, 0, stream>>>(Hcb, Xpb, Wihb, Whhb, bih, bhh, out, N);
}